// Round 20
// baseline (106.715 us; speedup 1.0000x reference)
//
#include <hip/hip_runtime.h>

#define B_ 64
#define L_ 1024
#define M_ 256
#define F_ 256

typedef __attribute__((ext_vector_type(8))) short short8;    // 8 bf16 (4 VGPR)
typedef __attribute__((ext_vector_type(16))) float f32x16;   // 32x32 MFMA C/D
typedef unsigned int u32;

struct Frag3 { short8 h, m, l; };

__device__ __forceinline__ u32 asu(float f) { union { float f; u32 u; } c; c.f = f; return c.u; }
__device__ __forceinline__ float asf(u32 u) { union { float f; u32 u; } c; c.u = u; return c.f; }
__device__ __forceinline__ u32 pack2(u32 lo, u32 hi) {
    return __builtin_amdgcn_perm(hi, lo, 0x07060302u);
}
__device__ __forceinline__ float4 ld4(const float* p) {
    return *reinterpret_cast<const float4*>(p);
}

// Async 16B global->LDS DMA; LDS dest wave-uniform, per-lane source carries
// the XOR swizzle (m173 pattern, validated R6/R10).
__device__ __forceinline__ void async_cp16(const float* g, float* l) {
    __builtin_amdgcn_global_load_lds(
        (const __attribute__((address_space(1))) u32*)g,
        (__attribute__((address_space(3))) u32*)l,
        16, 0, 0);
}

// Exact 3-way bf16 truncation split of 8 fp32: x = h + m + l (top 24 mantissa bits).
__device__ __forceinline__ Frag3 split8(float4 a, float4 b) {
    float x[8] = {a.x, a.y, a.z, a.w, b.x, b.y, b.z, b.w};
    u32 xb[8], rb[8], sb[8];
#pragma unroll
    for (int e = 0; e < 8; ++e) {
        xb[e] = asu(x[e]);
        float hf = asf(xb[e] & 0xFFFF0000u);
        float r  = x[e] - hf;                 // exact
        rb[e] = asu(r);
        float mf = asf(rb[e] & 0xFFFF0000u);
        float r2 = r - mf;                    // exact
        sb[e] = asu(r2);
    }
    union { u32 w[4]; short8 s; } H, M, Lo;
#pragma unroll
    for (int d = 0; d < 4; ++d) {
        H.w[d]  = pack2(xb[2 * d], xb[2 * d + 1]);
        M.w[d]  = pack2(rb[2 * d], rb[2 * d + 1]);
        Lo.w[d] = pack2(sb[2 * d], sb[2 * d + 1]);
    }
    Frag3 f; f.h = H.s; f.m = M.s; f.l = Lo.s; return f;
}

#define MFMA6(ACC, A, Bf)                                                        \
    ACC = __builtin_amdgcn_mfma_f32_32x32x16_bf16((A).m, (Bf).m, ACC, 0, 0, 0);  \
    ACC = __builtin_amdgcn_mfma_f32_32x32x16_bf16((A).h, (Bf).l, ACC, 0, 0, 0);  \
    ACC = __builtin_amdgcn_mfma_f32_32x32x16_bf16((A).l, (Bf).h, ACC, 0, 0, 0);  \
    ACC = __builtin_amdgcn_mfma_f32_32x32x16_bf16((A).h, (Bf).m, ACC, 0, 0, 0);  \
    ACC = __builtin_amdgcn_mfma_f32_32x32x16_bf16((A).m, (Bf).h, ACC, 0, 0, 0);  \
    ACC = __builtin_amdgcn_mfma_f32_32x32x16_bf16((A).h, (Bf).h, ACC, 0, 0, 0)

// One block per l, 256 threads = 4 waves, SINGLE-buffered LDS 40960 B ->
// 4 blocks/CU = 4 independent de-phased HBM request queues per CU (the
// un-isolated axis: R13/R18 had 2). Per tile: barrier -> STAGE -> vmcnt(0)
// -> barrier -> compute; the in-block stage stall is covered by the other
// 3 blocks. Wave (bt=w&1, mtg=w>>1): b-rows bt*32..+31, m-cols mtg*128..+127.
// D layout: col(m)=lane&31, row=(reg&3)+8*(reg>>2)+4*(lane>>5)  [m74/m101].
__launch_bounds__(256, 2)
__global__ void mq_mfma_sb4_kernel(const float* __restrict__ patch,
                                   const float* __restrict__ queue,
                                   float* __restrict__ out) {
    const int l    = blockIdx.x;
    const int t    = threadIdx.x;
    const int lane = t & 63;
    const int w    = t >> 6;        // 0..3
    const int bt   = w & 1;
    const int mtg  = w >> 1;        // 0..1
    const int r32  = lane & 31;
    const int kh   = lane >> 5;     // k-half: f-offset kh*8

    __shared__ __align__(16) float Ql[256 * 32];  // 32KB, slot = chunk^(row&7)
    __shared__ __align__(16) float Pl[64 * 32];   //  8KB   (total 40960 B)

    // staging geometry (R6, proven): wave w stages Q rows w*64..+63 (8 chunks)
    // and P rows w*16..+15 (2 chunks); swizzled source chunk lcol^lrow.
    const int lrow = lane >> 3;     // 0..7: row within an 8-row chunk
    const int lcol = lane & 7;      // 0..7: 16B slot within a 128B row
    const float* qsrcw = queue + ((size_t)l * M_ + w * 64 + lrow) * F_ + (lcol ^ lrow) * 4;
    const float* psrcw = patch + ((size_t)(w * 16 + lrow) * L_ + l) * F_ + (lcol ^ lrow) * 4;

    f32x16 acc[4];
#pragma unroll
    for (int mt = 0; mt < 4; ++mt) acc[mt] = (f32x16)0.f;

    const int s7 = r32 & 7;          // read-side XOR (row&7 == r32&7 everywhere)
    const int ra = bt * 32 + r32;    // P row for this lane

#pragma unroll 1
    for (int ft = 0; ft < 8; ++ft) {
        // barrier#1: all waves done reading tile ft-1 -> buffer reusable.
        __builtin_amdgcn_s_barrier();
        __builtin_amdgcn_sched_barrier(0);
        {
            const int o = ft * 32;
#pragma unroll
            for (int k = 0; k < 8; ++k)
                async_cp16(qsrcw + (size_t)k * 8 * F_ + o, &Ql[(w * 8 + k) * 256]);
#pragma unroll
            for (int k = 0; k < 2; ++k)
                async_cp16(psrcw + (size_t)k * 8 * L_ * F_ + o, &Pl[(w * 2 + k) * 256]);
        }
        asm volatile("s_waitcnt vmcnt(0)" ::: "memory");
        __builtin_amdgcn_sched_barrier(0);
        // barrier#2: every wave's tile-ft chunks landed.
        __builtin_amdgcn_s_barrier();
        __builtin_amdgcn_sched_barrier(0);

#pragma unroll
        for (int kk = 0; kk < 2; ++kk) {
            const int c0 = kk * 4 + kh * 2;   // first 16B chunk of this fragment
            const float4 a0 = ld4(&Pl[ra * 32 + ((c0 ^ s7) * 4)]);
            const float4 a1 = ld4(&Pl[ra * 32 + (((c0 + 1) ^ s7) * 4)]);
            const Frag3 A = split8(a0, a1);
#pragma unroll
            for (int mt = 0; mt < 4; ++mt) {
                const int rb = mtg * 128 + mt * 32 + r32;
                const float4 b0 = ld4(&Ql[rb * 32 + ((c0 ^ s7) * 4)]);
                const float4 b1 = ld4(&Ql[rb * 32 + (((c0 + 1) ^ s7) * 4)]);
                const Frag3 Bf = split8(b0, b1);
                MFMA6(acc[mt], A, Bf);
            }
        }
    }

    __syncthreads();   // all compute done before scratch overlays Pl

    // argmax over m per b (numpy first-occurrence; logic as R8/R10).
    float* pval = (float*)&Pl[0];          // [2][64]
    int*   pidx = (int*)&Pl[0] + 128;      // [2][64]
    int*   sidx = (int*)&Pl[0] + 256;      // [64]
#pragma unroll
    for (int r = 0; r < 16; ++r) {
        float bv = acc[0][r];
        int   bi = mtg * 128 + r32;
#pragma unroll
        for (int mt = 1; mt < 4; ++mt) {
            const float cv = acc[mt][r];
            const int   ci = mtg * 128 + mt * 32 + r32;
            if (cv > bv) { bv = cv; bi = ci; }
        }
#pragma unroll
        for (int off = 16; off >= 1; off >>= 1) {
            const float ov = __shfl_xor(bv, off);
            const int   oi = __shfl_xor(bi, off);
            if (ov > bv || (ov == bv && oi < bi)) { bv = ov; bi = oi; }
        }
        if (r32 == 0) {
            const int b = bt * 32 + (r & 3) + 8 * (r >> 2) + 4 * kh;
            pval[mtg * 64 + b] = bv;
            pidx[mtg * 64 + b] = bi;
        }
    }
    __syncthreads();

    // Combine the two m-halves; mtg0 (lower m) wins ties -> first occurrence.
    if (t < 64) {
        const float v0 = pval[t], v1 = pval[64 + t];
        sidx[t] = (v1 > v0) ? pidx[64 + t] : pidx[t];
    }
    __syncthreads();

    // gather: out[b][l][:] = queue[l][sidx[b]][:]  (queue[l] is L2-hot)
    const int cb = t >> 6;     // 0..3
    const int cc = t & 63;     // float4 index within the 256-float row
#pragma unroll
    for (int b0 = 0; b0 < 64; b0 += 4) {
        const int b  = b0 + cb;
        const int mi = sidx[b];
        const float4 v = ld4(&queue[((size_t)l * M_ + mi) * F_ + cc * 4]);
        *reinterpret_cast<float4*>(&out[((size_t)b * L_ + l) * F_ + cc * 4]) = v;
    }
}

extern "C" void kernel_launch(void* const* d_in, const int* in_sizes, int n_in,
                              void* d_out, int out_size, void* d_ws, size_t ws_size,
                              hipStream_t stream) {
    const float* patch = (const float*)d_in[0];
    const float* queue = (const float*)d_in[1];
    float* out = (float*)d_out;
    mq_mfma_sb4_kernel<<<dim3(L_), dim3(256), 0, stream>>>(patch, queue, out);
}

// Round 21
// 106.354 us; speedup vs baseline: 1.0034x; 1.0034x over previous
//
#include <hip/hip_runtime.h>

#define B_ 64
#define L_ 1024
#define M_ 256
#define F_ 256

typedef __attribute__((ext_vector_type(8))) short short8;    // 8 bf16 (4 VGPR)
typedef __attribute__((ext_vector_type(16))) float f32x16;   // 32x32 MFMA C/D
typedef unsigned int u32;

struct Frag3 { short8 h, m, l; };

__device__ __forceinline__ u32 asu(float f) { union { float f; u32 u; } c; c.f = f; return c.u; }
__device__ __forceinline__ float asf(u32 u) { union { float f; u32 u; } c; c.u = u; return c.f; }
__device__ __forceinline__ u32 pack2(u32 lo, u32 hi) {
    return __builtin_amdgcn_perm(hi, lo, 0x07060302u);
}
__device__ __forceinline__ float4 ld4(const float* p) {
    return *reinterpret_cast<const float4*>(p);
}

// Async 16B global->LDS DMA; LDS dest wave-uniform, per-lane source carries
// the XOR swizzle (m173 pattern, validated R6/R10).
__device__ __forceinline__ void async_cp16(const float* g, float* l) {
    __builtin_amdgcn_global_load_lds(
        (const __attribute__((address_space(1))) u32*)g,
        (__attribute__((address_space(3))) u32*)l,
        16, 0, 0);
}

// Exact 3-way bf16 truncation split of 8 fp32: x = h + m + l (top 24 mantissa bits).
__device__ __forceinline__ Frag3 split8(float4 a, float4 b) {
    float x[8] = {a.x, a.y, a.z, a.w, b.x, b.y, b.z, b.w};
    u32 xb[8], rb[8], sb[8];
#pragma unroll
    for (int e = 0; e < 8; ++e) {
        xb[e] = asu(x[e]);
        float hf = asf(xb[e] & 0xFFFF0000u);
        float r  = x[e] - hf;                 // exact
        rb[e] = asu(r);
        float mf = asf(rb[e] & 0xFFFF0000u);
        float r2 = r - mf;                    // exact
        sb[e] = asu(r2);
    }
    union { u32 w[4]; short8 s; } H, M, Lo;
#pragma unroll
    for (int d = 0; d < 4; ++d) {
        H.w[d]  = pack2(xb[2 * d], xb[2 * d + 1]);
        M.w[d]  = pack2(rb[2 * d], rb[2 * d + 1]);
        Lo.w[d] = pack2(sb[2 * d], sb[2 * d + 1]);
    }
    Frag3 f; f.h = H.s; f.m = M.s; f.l = Lo.s; return f;
}

#define MFMA6(ACC, A, Bf)                                                        \
    ACC = __builtin_amdgcn_mfma_f32_32x32x16_bf16((A).m, (Bf).m, ACC, 0, 0, 0);  \
    ACC = __builtin_amdgcn_mfma_f32_32x32x16_bf16((A).h, (Bf).l, ACC, 0, 0, 0);  \
    ACC = __builtin_amdgcn_mfma_f32_32x32x16_bf16((A).l, (Bf).h, ACC, 0, 0, 0);  \
    ACC = __builtin_amdgcn_mfma_f32_32x32x16_bf16((A).h, (Bf).m, ACC, 0, 0, 0);  \
    ACC = __builtin_amdgcn_mfma_f32_32x32x16_bf16((A).m, (Bf).h, ACC, 0, 0, 0);  \
    ACC = __builtin_amdgcn_mfma_f32_32x32x16_bf16((A).h, (Bf).h, ACC, 0, 0, 0)

// One block per l, 512 threads = 8 waves, SINGLE-buffered LDS 80KB ->
// 2 blocks/CU. K-tile = 64 f: every DMA chunk is 256B per row (vs 128B at
// K=32) -> 2x DRAM page efficiency (the theory: all 20 prior rounds capped
// at ~3 TB/s because 128B-per-1KB-row reads waste DRAM page activates).
// Rows are 16 16B-slots; slot = chunk ^ (row&15), pre-swizzled at source.
// Wave (bt=w&1, mtg=w>>1): b-rows bt*32..+31, m-cols mtg*64..+63; 4 K-tiles
// x 4 k-steps of 16 f -- same accumulation sequence as R13/R18 -> absmax 0.
// D layout: col(m)=lane&31, row=(reg&3)+8*(reg>>2)+4*(lane>>5)  [m74/m101].
__launch_bounds__(512, 2)
__global__ void mq_mfma_k64_kernel(const float* __restrict__ patch,
                                   const float* __restrict__ queue,
                                   float* __restrict__ out) {
    const int l    = blockIdx.x;
    const int t    = threadIdx.x;
    const int lane = t & 63;
    const int w    = t >> 6;        // 0..7
    const int bt   = w & 1;
    const int mtg  = w >> 1;        // 0..3
    const int r32  = lane & 31;
    const int kh   = lane >> 5;     // k-half: f-offset kh*8

    __shared__ __align__(16) float Ql[256 * 64];  // 64KB, 16 slots/row
    __shared__ __align__(16) float Pl[64 * 64];   // 16KB   (total 80KB)

    // staging geometry: 4-row cp16 groups; lane = (lrow4 = lane>>4, lslot).
    const int lrow4 = lane >> 4;    // 0..3: row within a 4-row group
    const int lslot = lane & 15;    // 0..15: 16B slot within a 256B row-chunk

    f32x16 acc0 = (f32x16)0.f, acc1 = (f32x16)0.f;

    const int s15 = r32 & 15;        // read-side XOR (row&15 == r32&15 everywhere)
    const int ra  = bt * 32 + r32;   // P row for this lane
    const int rb0 = mtg * 64 + r32;  // first Q row
    const int rb1 = mtg * 64 + 32 + r32;

#pragma unroll 1
    for (int kt = 0; kt < 4; ++kt) {
        // barrier#1: all waves done reading tile kt-1 -> buffer reusable.
        __builtin_amdgcn_s_barrier();
        __builtin_amdgcn_sched_barrier(0);
        {
            const int o = kt * 64;
            // Q: wave w stages groups g = w*8+k (rows g*4..g*4+3), 8 cp16.
#pragma unroll
            for (int k = 0; k < 8; ++k) {
                const int g   = w * 8 + k;
                const int row = g * 4 + lrow4;
                async_cp16(queue + ((size_t)l * M_ + row) * F_ + o
                                 + ((lslot ^ (row & 15)) * 4),
                           &Ql[(g * 4) * 64]);
            }
            // P: wave w stages groups pg = w*2+k2 (rows pg*4..pg*4+3), 2 cp16.
#pragma unroll
            for (int k2 = 0; k2 < 2; ++k2) {
                const int pg  = w * 2 + k2;
                const int row = pg * 4 + lrow4;
                async_cp16(patch + ((size_t)row * L_ + l) * F_ + o
                                 + ((lslot ^ (row & 15)) * 4),
                           &Pl[(pg * 4) * 64]);
            }
        }
        asm volatile("s_waitcnt vmcnt(0)" ::: "memory");
        __builtin_amdgcn_sched_barrier(0);
        // barrier#2: every wave's tile-kt chunks landed.
        __builtin_amdgcn_s_barrier();
        __builtin_amdgcn_sched_barrier(0);

#pragma unroll
        for (int kk = 0; kk < 4; ++kk) {
            const int c0 = kk * 4 + kh * 2;   // first 16B slot of this fragment
            const float4 a0 = ld4(&Pl[ra * 64 + ((c0 ^ s15) * 4)]);
            const float4 a1 = ld4(&Pl[ra * 64 + (((c0 + 1) ^ s15) * 4)]);
            const Frag3 A = split8(a0, a1);
            {
                const float4 b0 = ld4(&Ql[rb0 * 64 + ((c0 ^ s15) * 4)]);
                const float4 b1 = ld4(&Ql[rb0 * 64 + (((c0 + 1) ^ s15) * 4)]);
                const Frag3 Bf = split8(b0, b1);
                MFMA6(acc0, A, Bf);
            }
            {
                const float4 b0 = ld4(&Ql[rb1 * 64 + ((c0 ^ s15) * 4)]);
                const float4 b1 = ld4(&Ql[rb1 * 64 + (((c0 + 1) ^ s15) * 4)]);
                const Frag3 Bf = split8(b0, b1);
                MFMA6(acc1, A, Bf);
            }
        }
    }

    __syncthreads();   // all compute done before scratch overlays Pl

    // argmax over m per b (numpy first-occurrence; logic identical to R13).
    float* pval = (float*)&Pl[0];          // [4][64]
    int*   pidx = (int*)&Pl[0] + 256;      // [4][64]
    int*   sidx = (int*)&Pl[0] + 512;      // [64]
#pragma unroll
    for (int r = 0; r < 16; ++r) {
        float bv = acc0[r];
        int   bi = mtg * 64 + r32;
        {
            const float cv = acc1[r];
            const int   ci = mtg * 64 + 32 + r32;
            if (cv > bv) { bv = cv; bi = ci; }
        }
#pragma unroll
        for (int off = 16; off >= 1; off >>= 1) {
            const float ov = __shfl_xor(bv, off);
            const int   oi = __shfl_xor(bi, off);
            if (ov > bv || (ov == bv && oi < bi)) { bv = ov; bi = oi; }
        }
        if (r32 == 0) {
            const int b = bt * 32 + (r & 3) + 8 * (r >> 2) + 4 * kh;
            pval[mtg * 64 + b] = bv;
            pidx[mtg * 64 + b] = bi;
        }
    }
    __syncthreads();

    // Combine the four m-quarters; ascending mtg with strict '>' keeps the
    // lowest m on ties -> numpy first-occurrence.
    if (t < 64) {
        float bv = pval[t];
        int   bi = pidx[t];
#pragma unroll
        for (int g = 1; g < 4; ++g) {
            const float cv = pval[g * 64 + t];
            if (cv > bv) { bv = cv; bi = pidx[g * 64 + t]; }
        }
        sidx[t] = bi;
    }
    __syncthreads();

    // gather: out[b][l][:] = queue[l][sidx[b]][:]  (queue[l] is L2-hot)
    const int cb = t >> 6;     // 0..7
    const int cc = t & 63;     // float4 index within the 256-float row
#pragma unroll
    for (int b0 = 0; b0 < 64; b0 += 8) {
        const int b  = b0 + cb;
        const int mi = sidx[b];
        const float4 v = ld4(&queue[((size_t)l * M_ + mi) * F_ + cc * 4]);
        *reinterpret_cast<float4*>(&out[((size_t)b * L_ + l) * F_ + cc * 4]) = v;
    }
}

extern "C" void kernel_launch(void* const* d_in, const int* in_sizes, int n_in,
                              void* d_out, int out_size, void* d_ws, size_t ws_size,
                              hipStream_t stream) {
    const float* patch = (const float*)d_in[0];
    const float* queue = (const float*)d_in[1];
    float* out = (float*)d_out;
    mq_mfma_k64_kernel<<<dim3(L_), dim3(512), 0, stream>>>(patch, queue, out);
}